// Round 11
// baseline (134.028 us; speedup 1.0000x reference)
//
#include <hip/hip_runtime.h>
#include <stdint.h>

#define S_LEN 2048
#define NHEADS 16
#define DHEAD 64
#define DMODEL 1024

typedef unsigned short u16;
typedef unsigned int u32;
typedef __bf16 bf16x8 __attribute__((ext_vector_type(8)));
typedef float f32x4 __attribute__((ext_vector_type(4)));
typedef float f32x16 __attribute__((ext_vector_type(16)));
typedef u32 u32x4 __attribute__((ext_vector_type(4)));
typedef u32 u32x2 __attribute__((ext_vector_type(2)));

__device__ __forceinline__ float bf2f(u16 u) {
  u32 x = ((u32)u) << 16;
  float f;
  __builtin_memcpy(&f, &x, 4);
  return f;
}
__device__ __forceinline__ u16 f2bf(float f) {
  u32 x;
  __builtin_memcpy(&x, &f, 4);
  x += 0x7FFFu + ((x >> 16) & 1u);
  return (u16)(x >> 16);
}
// packed f32 pair -> bf16 pair (lo = a, hi = b)
__device__ __forceinline__ u32 cvtpk(float a, float b) {
  u32 r;
  asm("v_cvt_pk_bf16_f32 %0, %1, %2" : "=v"(r) : "v"(a), "v"(b));
  return r;
}
// r[0] = {a_lo, b_lo}, r[1] = {a_hi, b_hi}
__device__ __forceinline__ u32x2 plswap2(u32 a, u32 b) {
  return __builtin_amdgcn_permlane32_swap(a, b, false, false);
}
// single-instruction exp2
__device__ __forceinline__ float fexp2(float x) {
  float r;
  asm("v_exp_f32 %0, %1" : "=v"(r) : "v"(x));
  return r;
}

#define AS1 __attribute__((address_space(1)))
#define AS3 __attribute__((address_space(3)))
__device__ __forceinline__ void gload16(const void* g, void* l) {
  __builtin_amdgcn_global_load_lds((AS1 void*)g, (AS3 void*)l, 16, 0, 0);
}

#define MFMA16(a, b, c) __builtin_amdgcn_mfma_f32_16x16x32_bf16(a, b, c, 0, 0, 0)
#define MFMA32(a, b, c) __builtin_amdgcn_mfma_f32_32x32x16_bf16(a, b, c, 0, 0, 0)

// ---------------- f32 -> bf16 convert: x (4 parts of 1M) + 4 weight mats ----
__global__ __launch_bounds__(256) void convert_k(
    const float* __restrict__ x, const float* __restrict__ wq, const float* __restrict__ wk,
    const float* __restrict__ wv, const float* __restrict__ wo,
    u16* __restrict__ xb, u16* __restrict__ wqb, u16* __restrict__ wkb,
    u16* __restrict__ wvb, u16* __restrict__ wob) {
  int part = blockIdx.y;
  const float* src;
  u16* dst;
  size_t base = 0;
  if (part < 4) { src = x; dst = xb; base = (size_t)part << 20; }
  else if (part == 4) { src = wq; dst = wqb; }
  else if (part == 5) { src = wk; dst = wkb; }
  else if (part == 6) { src = wv; dst = wvb; }
  else { src = wo; dst = wob; }
  size_t i = base + ((size_t)(blockIdx.x * 256 + threadIdx.x)) * 4;
  float4 v = *(const float4*)(src + i);
  ushort4 o;
  o.x = f2bf(v.x); o.y = f2bf(v.y); o.z = f2bf(v.z); o.w = f2bf(v.w);
  *(ushort4*)(dst + i) = o;
}

// ---------------- shared 128x128 bf16 GEMM core, C = A * B^T ----------------
// SWAP=false: acc[mi][ni] = normal frag (row = A/m, col = B/n).
// SWAP=true:  acc[mi][ni] = transposed frag (row = B/n, col = A/m).
template <bool SWAP>
__device__ __forceinline__ void gemm_core(const u16* __restrict__ A,
                                          const u16* __restrict__ Bm,
                                          int m0, int n0, int t,
                                          u16* As, u16* Bs, f32x4 (&acc)[4][4]) {
  int w = t >> 6, lane = t & 63, lr = lane >> 4, lc = lane & 15;
  int wr = w >> 1, wc = w & 1;
  int srow = t >> 3;
  int scolb = (t & 7) * 16;
  const char* Ag = (const char*)A;
  const char* Bg = (const char*)Bm;
  for (int k0 = 0; k0 < DMODEL; k0 += 64) {
#pragma unroll
    for (int i = 0; i < 4; i++) {
      gload16(Ag + ((size_t)(m0 + srow + i * 32) * DMODEL + k0) * 2 + scolb,
              (char*)As + i * 4096 + w * 1024);
      gload16(Bg + ((size_t)(n0 + srow + i * 32) * DMODEL + k0) * 2 + scolb,
              (char*)Bs + i * 4096 + w * 1024);
    }
    __syncthreads();
#pragma unroll
    for (int kk = 0; kk < 2; kk++) {
      bf16x8 af[4], bfr[4];
#pragma unroll
      for (int mi = 0; mi < 4; mi++)
        af[mi] = *(const bf16x8*)(As + (wr * 64 + mi * 16 + lc) * 64 + kk * 32 + lr * 8);
#pragma unroll
      for (int ni = 0; ni < 4; ni++)
        bfr[ni] = *(const bf16x8*)(Bs + (wc * 64 + ni * 16 + lc) * 64 + kk * 32 + lr * 8);
#pragma unroll
      for (int mi = 0; mi < 4; mi++)
#pragma unroll
        for (int ni = 0; ni < 4; ni++) {
          if constexpr (SWAP)
            acc[mi][ni] = MFMA16(bfr[ni], af[mi], acc[mi][ni]);
          else
            acc[mi][ni] = MFMA16(af[mi], bfr[ni], acc[mi][ni]);
        }
    }
    __syncthreads();
  }
}

// ---------------- fused QKV projection: one dispatch, z in {0:Q,1:K,2:VT} ---
// z<2: swapped acc -> lane holds 2 rope pairs -> fused RoPE (Q gets 1/8
// scale) + 8B packed stores to [B,H,S,DK].  z==2: normal acc -> 4
// consecutive s per lane -> 8B stores to V^T [B,H,DK,S]. 768 blocks = 3/CU.
__global__ __launch_bounds__(256) void gemm_qkv(
    const u16* __restrict__ A, const u16* __restrict__ wq, const u16* __restrict__ wk,
    const u16* __restrict__ wv, u16* __restrict__ Qb, u16* __restrict__ Kb,
    u16* __restrict__ VTb, const int* __restrict__ pos) {
  __shared__ alignas(16) u16 As[128 * 64];
  __shared__ alignas(16) u16 Bs[128 * 64];
  int z = blockIdx.z;
  int m0 = blockIdx.x * 128, n0 = blockIdx.y * 128;
  int t = threadIdx.x;
  int w = t >> 6, lane = t & 63, lr = lane >> 4, lc = lane & 15;
  int wr = w >> 1, wc = w & 1;
  f32x4 acc[4][4] = {};
  if (z == 2) {
    gemm_core<false>(A, wv, m0, n0, t, As, Bs, acc);
    // normal frag: d = ni*16+lc, s = m0+wr*64+mi*16+lr*4+{0..3}
    int bh = (m0 >> 11) * NHEADS + (n0 >> 6) + wc;
    int scol = (m0 & 2047) + wr * 64;
#pragma unroll
    for (int mi = 0; mi < 4; mi++)
#pragma unroll
      for (int ni = 0; ni < 4; ni++) {
        int d = ni * 16 + lc;
        f32x4 a = acc[mi][ni];
        uint2 pk;
        pk.x = cvtpk(a[0], a[1]);
        pk.y = cvtpk(a[2], a[3]);
        *(uint2*)(VTb + ((size_t)bh * DHEAD + d) * S_LEN + scol + mi * 16 + lr * 4) = pk;
      }
  } else {
    gemm_core<true>(A, z ? wk : wq, m0, n0, t, As, Bs, acc);
    // swapped frag: s = ...+lc, d = ni*16+lr*4+{0..3} = 2 rope pairs
    u16* Oh = z ? Kb : Qb;
    float oscale = z ? 1.0f : 0.125f;  // fold 1/sqrt(DK) into Q
    int h = (n0 >> 6) + wc;
    float fr0[4], fr1[4];
#pragma unroll
    for (int ni = 0; ni < 4; ni++) {
      int i0 = ni * 8 + lr * 2;  // pair index = d/2
      fr0[ni] = exp2f(-0.4152410118407687f * (float)i0);
      fr1[ni] = exp2f(-0.4152410118407687f * (float)(i0 + 1));
    }
#pragma unroll
    for (int mi = 0; mi < 4; mi++) {
      int sg = m0 + wr * 64 + mi * 16 + lc;
      float p = (float)pos[sg];
      int b = sg >> 11, s = sg & 2047;
      u16* dst = Oh + ((size_t)((b * NHEADS + h) * S_LEN + s)) * DHEAD;
#pragma unroll
      for (int ni = 0; ni < 4; ni++) {
        float sn0, cs0, sn1, cs1;
        __sincosf(p * fr0[ni], &sn0, &cs0);
        __sincosf(p * fr1[ni], &sn1, &cs1);
        f32x4 a = acc[mi][ni];
        uint2 pk;
        pk.x = cvtpk((a[0] * cs0 - a[1] * sn0) * oscale,
                     (a[0] * sn0 + a[1] * cs0) * oscale);
        pk.y = cvtpk((a[2] * cs1 - a[3] * sn1) * oscale,
                     (a[2] * sn1 + a[3] * cs1) * oscale);
        *(uint2*)(dst + ni * 16 + lr * 4) = pk;
      }
    }
  }
}

// ---------------- output projection: f32 [M][N], swapped acc -> float4 -----
__global__ __launch_bounds__(256) void gemm_out(const u16* __restrict__ A,
                                                const u16* __restrict__ wo,
                                                float* __restrict__ Of) {
  __shared__ alignas(16) u16 As[128 * 64];
  __shared__ alignas(16) u16 Bs[128 * 64];
  int m0 = blockIdx.x * 128, n0 = blockIdx.y * 128;
  int t = threadIdx.x;
  int w = t >> 6, lane = t & 63, lr = lane >> 4, lc = lane & 15;
  int wr = w >> 1, wc = w & 1;
  f32x4 acc[4][4] = {};
  gemm_core<true>(A, wo, m0, n0, t, As, Bs, acc);
#pragma unroll
  for (int mi = 0; mi < 4; mi++) {
    int m = m0 + wr * 64 + mi * 16 + lc;
#pragma unroll
    for (int ni = 0; ni < 4; ni++) {
      int n = n0 + wc * 64 + ni * 16 + lr * 4;
      *(f32x4*)(Of + (size_t)m * DMODEL + n) = acc[mi][ni];
    }
  }
}

// ---------------- causal flash attention, v11: paired q-tiles --------------
// Block (bh, y in [0,8)) handles q-tiles qcA=y and qcB=15-y on one KV sweep:
// stage s feeds B always, A while s<=qcA. Per-block compute = 17 stage-
// equivalents (uniform; kills the R10 imbalance tail where CU tile-loads
// ranged 20..48). K/V staged once for two q-tiles. Grid 256 = 1 block/CU.
struct AttnSt {
  f32x16 oacc[2];
  float mrun, lrun;
};

__device__ __forceinline__ void attn_tile64(
    const char* kbuf, const char* vbuf, int tb, int kv0, bool domask,
    const bf16x8 (&qf)[4], int qrow, int h, int ql, AttnSt& st) {
  const float L2E = 1.4426950408889634f;
  int swz = ql & 7;
  // S^T = K * Q^T
  f32x16 sacc[2] = {};
  __builtin_amdgcn_s_setprio(1);
#pragma unroll
  for (int kt = 0; kt < 4; kt++) {
    int c = ((2 * kt + h) ^ swz) << 4;
    const char* kr = kbuf + (size_t)tb * 8192;
    bf16x8 k0 = *(const bf16x8*)(kr + ql * 128 + c);
    bf16x8 k1 = *(const bf16x8*)(kr + (32 + ql) * 128 + c);
    sacc[0] = MFMA32(k0, qf[kt], sacc[0]);
    sacc[1] = MFMA32(k1, qf[kt], sacc[1]);
  }
  __builtin_amdgcn_s_setprio(0);
  if (domask) {
#pragma unroll
    for (int r = 0; r < 16; r++) {
      int kvb = kv0 + (r & 3) + 8 * (r >> 2) + 4 * h;
      if (kvb > qrow) sacc[0][r] = -1e30f;
      if (kvb + 32 > qrow) sacc[1][r] = -1e30f;
    }
  }
  // row max: in-register tree + cross-half shfl
  float t8[8];
#pragma unroll
  for (int r = 0; r < 8; r++)
    t8[r] = fmaxf(fmaxf(sacc[0][r], sacc[0][r + 8]), fmaxf(sacc[1][r], sacc[1][r + 8]));
  float t4a = fmaxf(t8[0], t8[4]), t4b = fmaxf(t8[1], t8[5]);
  float t4c = fmaxf(t8[2], t8[6]), t4d = fmaxf(t8[3], t8[7]);
  float mx = fmaxf(fmaxf(t4a, t4b), fmaxf(t4c, t4d));
  mx = fmaxf(mx, __shfl_xor(mx, 32));
  bool up = mx > st.mrun + 5.5451774444795624f;  // defer-max, THR=8*ln2
  if (__any(up)) {
    float newm = up ? mx : st.mrun;
    float scl = fexp2((st.mrun - newm) * L2E);
    st.mrun = newm;
    st.lrun *= scl;
#pragma unroll
    for (int r = 0; r < 16; r++) { st.oacc[0][r] *= scl; st.oacc[1][r] *= scl; }
  }
  float nm2 = -st.mrun * L2E;
#pragma unroll
  for (int r = 0; r < 16; r++) {
    sacc[0][r] = fexp2(__builtin_fmaf(sacc[0][r], L2E, nm2));
    sacc[1][r] = fexp2(__builtin_fmaf(sacc[1][r], L2E, nm2));
  }
  float u8[8];
#pragma unroll
  for (int r = 0; r < 8; r++)
    u8[r] = (sacc[0][r] + sacc[0][r + 8]) + (sacc[1][r] + sacc[1][r + 8]);
  st.lrun += ((u8[0] + u8[4]) + (u8[1] + u8[5])) + ((u8[2] + u8[6]) + (u8[3] + u8[7]));
  // P^T -> bf16 B-frags
  u32x4 pa[4];
#pragma unroll
  for (int tau = 0; tau < 2; tau++) {
    u32x2 rA = plswap2(cvtpk(sacc[tau][0], sacc[tau][1]), cvtpk(sacc[tau][4], sacc[tau][5]));
    pa[2 * tau][0] = rA[0]; pa[2 * tau][2] = rA[1];
    u32x2 rC = plswap2(cvtpk(sacc[tau][2], sacc[tau][3]), cvtpk(sacc[tau][6], sacc[tau][7]));
    pa[2 * tau][1] = rC[0]; pa[2 * tau][3] = rC[1];
    u32x2 rA1 = plswap2(cvtpk(sacc[tau][8], sacc[tau][9]), cvtpk(sacc[tau][12], sacc[tau][13]));
    pa[2 * tau + 1][0] = rA1[0]; pa[2 * tau + 1][2] = rA1[1];
    u32x2 rC1 = plswap2(cvtpk(sacc[tau][10], sacc[tau][11]), cvtpk(sacc[tau][14], sacc[tau][15]));
    pa[2 * tau + 1][1] = rC1[0]; pa[2 * tau + 1][3] = rC1[1];
  }
  // O^T += V^T * P^T
  __builtin_amdgcn_s_setprio(1);
#pragma unroll
  for (int kt = 0; kt < 4; kt++) {
    int c = (tb * 8 + ((2 * kt + h) ^ swz)) << 4;
    bf16x8 v0 = *(const bf16x8*)(vbuf + ql * 256 + c);
    bf16x8 v1 = *(const bf16x8*)(vbuf + (32 + ql) * 256 + c);
    bf16x8 pb = __builtin_bit_cast(bf16x8, pa[kt]);
    st.oacc[0] = MFMA32(v0, pb, st.oacc[0]);
    st.oacc[1] = MFMA32(v1, pb, st.oacc[1]);
  }
  __builtin_amdgcn_s_setprio(0);
}

__device__ __forceinline__ void attn_store(const AttnSt& st, u16* __restrict__ O,
                                           int bh, int qrow, int h) {
  float lsum = st.lrun + __shfl_xor(st.lrun, 32);
  float inv = 1.0f / lsum;
  int b = bh >> 4, hd = bh & 15;
  u16* Orow = O + ((size_t)(b * S_LEN + qrow)) * DMODEL + hd * 64;
#pragma unroll
  for (int dt = 0; dt < 2; dt++)
#pragma unroll
    for (int rr = 0; rr < 4; rr++) {
      uint2 pk;
      pk.x = cvtpk(st.oacc[dt][4 * rr + 0] * inv, st.oacc[dt][4 * rr + 1] * inv);
      pk.y = cvtpk(st.oacc[dt][4 * rr + 2] * inv, st.oacc[dt][4 * rr + 3] * inv);
      *(uint2*)(Orow + 32 * dt + 8 * rr + 4 * h) = pk;
    }
}

__global__ __launch_bounds__(256, 1) void attn_k(const u16* __restrict__ Q,
                                                 const u16* __restrict__ K,
                                                 const u16* __restrict__ VT,
                                                 u16* __restrict__ O) {
  __shared__ alignas(16) u16 Ks[2][128 * 64];  // [kv][d], swizzled, 16KB each
  __shared__ alignas(16) u16 Vs[2][64 * 128];  // [d][kv], swizzled, 16KB each
  int bh = blockIdx.x;       // fast dim -> bh%8 tracks XCD
  int y = blockIdx.y;        // 0..7
  int qcA = y, qcB = 15 - y; // paired q-tiles: (y+1)+(16-y) = 17 stages/block
  int t = threadIdx.x, w = t >> 6, lane = t & 63;
  int ql = lane & 31, h = lane >> 5;
  size_t base = (size_t)bh * (S_LEN * DHEAD);
  int qrowA = qcA * 128 + w * 32 + ql;
  int qrowB = qcB * 128 + w * 32 + ql;
  bf16x8 qfA[4], qfB[4];
#pragma unroll
  for (int kt = 0; kt < 4; kt++) {
    qfA[kt] = *(const bf16x8*)(Q + base + (size_t)qrowA * DHEAD + kt * 16 + h * 8);
    qfB[kt] = *(const bf16x8*)(Q + base + (size_t)qrowB * DHEAD + kt * 16 + h * 8);
  }
  AttnSt stA, stB;
  stA.oacc[0] = f32x16{}; stA.oacc[1] = f32x16{}; stA.mrun = -1e30f; stA.lrun = 0.0f;
  stB.oacc[0] = f32x16{}; stB.oacc[1] = f32x16{}; stB.mrun = -1e30f; stB.lrun = 0.0f;
  // staging source pointers (pre-swizzled global chunks; LDS dest is linear)
  int krow = t >> 3;
  int kc = ((t & 7) ^ (krow & 7)) << 3;  // u16 units
  const u16* Kg0 = K + base + (size_t)krow * DHEAD + kc;
  int vrow = t >> 4;
  int vc = ((t & 15) ^ (vrow & 7)) << 3;  // u16 units
  const u16* Vg0 = VT + (size_t)bh * DHEAD * S_LEN + (size_t)vrow * S_LEN + vc;
  char* klb = (char*)&Ks[0][0] + w * 1024;
  char* vlb = (char*)&Vs[0][0] + w * 1024;

#define STAGE(s, buf)                                                    \
  do {                                                                   \
    int kv0s = (s) * 128;                                                \
    char* kl = klb + (buf) * 16384;                                      \
    char* vl = vlb + (buf) * 16384;                                      \
    _Pragma("unroll")                                                    \
    for (int p = 0; p < 4; p++)                                          \
      gload16(Kg0 + (size_t)(kv0s + p * 32) * DHEAD, kl + p * 4096);     \
    _Pragma("unroll")                                                    \
    for (int p = 0; p < 4; p++)                                          \
      gload16(Vg0 + (size_t)(p * 16) * S_LEN + kv0s, vl + p * 4096);     \
  } while (0)

  STAGE(0, 0);
  asm volatile("s_waitcnt vmcnt(0)" ::: "memory");
  __builtin_amdgcn_s_barrier();
  asm volatile("" ::: "memory");
  int cur = 0;
#pragma unroll 1
  for (int s = 0; s <= qcB; ++s) {
    if (s < qcB) STAGE(s + 1, cur ^ 1);  // loads in flight across this stage
    const char* kb = (const char*)&Ks[cur][0];
    const char* vb = (const char*)&Vs[cur][0];
    bool actA = (s <= qcA);
    bool diagA = (s == qcA), diagB = (s == qcB);
    // tile a: kv [128s, 128s+64)  (A and B calls are independent -> ILP)
    if (actA) attn_tile64(kb, vb, 0, s * 128, diagA && (w < 2), qfA, qrowA, h, ql, stA);
    attn_tile64(kb, vb, 0, s * 128, diagB && (w < 2), qfB, qrowB, h, ql, stB);
    // tile b: kv [128s+64, 128s+128); on a tile's diagonal stage waves 0,1 skip
    if (actA && !(diagA && w < 2))
      attn_tile64(kb, vb, 1, s * 128 + 64, diagA, qfA, qrowA, h, ql, stA);
    if (!(diagB && w < 2))
      attn_tile64(kb, vb, 1, s * 128 + 64, diagB, qfB, qrowB, h, ql, stB);
    asm volatile("s_waitcnt vmcnt(0)" ::: "memory");
    __builtin_amdgcn_s_barrier();
    asm volatile("" ::: "memory");
    cur ^= 1;
  }
#undef STAGE
  attn_store(stA, O, bh, qrowA, h);
  attn_store(stB, O, bh, qrowB, h);
}

// ---------------- launch -----------------------------------------------------
extern "C" void kernel_launch(void* const* d_in, const int* in_sizes, int n_in,
                              void* d_out, int out_size, void* d_ws, size_t ws_size,
                              hipStream_t stream) {
  (void)in_sizes; (void)n_in; (void)out_size; (void)ws_size;
  const float* x = (const float*)d_in[0];
  const int* tpos = (const int*)d_in[1];
  const float* Wq = (const float*)d_in[2];
  const float* Wk = (const float*)d_in[3];
  const float* Wv = (const float*)d_in[4];
  const float* Wo = (const float*)d_in[5];
  char* ws = (char*)d_ws;
  // workspace map (48 MB used of 56)
  u16* xb  = (u16*)(ws + ((size_t)0 << 20));   // 8 MB  [4096][1024] bf16
  u16* wqb = (u16*)(ws + ((size_t)8 << 20));   // 2 MB
  u16* wkb = (u16*)(ws + ((size_t)10 << 20));  // 2 MB
  u16* wvb = (u16*)(ws + ((size_t)12 << 20));  // 2 MB
  u16* wob = (u16*)(ws + ((size_t)14 << 20));  // 2 MB
  u16* Qb  = (u16*)(ws + ((size_t)16 << 20));  // 8 MB  [B,H,S,DK] (rope'd, scaled)
  u16* Kb  = (u16*)(ws + ((size_t)24 << 20));  // 8 MB  [B,H,S,DK] (rope'd)
  u16* VTb = (u16*)(ws + ((size_t)32 << 20));  // 8 MB  [B,H,DK,S]
  u16* Ob  = (u16*)(ws + ((size_t)40 << 20));  // 8 MB  [B,S,DMODEL] bf16

  convert_k<<<dim3(1024, 8), 256, 0, stream>>>(x, Wq, Wk, Wv, Wo, xb, wqb, wkb, wvb, wob);
  gemm_qkv<<<dim3(32, 8, 3), 256, 0, stream>>>(xb, wqb, wkb, wvb, Qb, Kb, VTb, tpos);
  attn_k<<<dim3(32, 8), 256, 0, stream>>>(Qb, Kb, VTb, Ob);
  gemm_out<<<dim3(32, 8), 256, 0, stream>>>(Ob, wob, (float*)d_out);
}

// Round 12
// 122.765 us; speedup vs baseline: 1.0917x; 1.0917x over previous
//
#include <hip/hip_runtime.h>
#include <stdint.h>

#define S_LEN 2048
#define NHEADS 16
#define DHEAD 64
#define DMODEL 1024

typedef unsigned short u16;
typedef unsigned int u32;
typedef __bf16 bf16x8 __attribute__((ext_vector_type(8)));
typedef float f32x4 __attribute__((ext_vector_type(4)));
typedef float f32x16 __attribute__((ext_vector_type(16)));
typedef u32 u32x4 __attribute__((ext_vector_type(4)));
typedef u32 u32x2 __attribute__((ext_vector_type(2)));

__device__ __forceinline__ float bf2f(u16 u) {
  u32 x = ((u32)u) << 16;
  float f;
  __builtin_memcpy(&f, &x, 4);
  return f;
}
__device__ __forceinline__ u16 f2bf(float f) {
  u32 x;
  __builtin_memcpy(&x, &f, 4);
  x += 0x7FFFu + ((x >> 16) & 1u);
  return (u16)(x >> 16);
}
// packed f32 pair -> bf16 pair (lo = a, hi = b)
__device__ __forceinline__ u32 cvtpk(float a, float b) {
  u32 r;
  asm("v_cvt_pk_bf16_f32 %0, %1, %2" : "=v"(r) : "v"(a), "v"(b));
  return r;
}
// r[0] = {a_lo, b_lo}, r[1] = {a_hi, b_hi}
__device__ __forceinline__ u32x2 plswap2(u32 a, u32 b) {
  return __builtin_amdgcn_permlane32_swap(a, b, false, false);
}
// single-instruction exp2
__device__ __forceinline__ float fexp2(float x) {
  float r;
  asm("v_exp_f32 %0, %1" : "=v"(r) : "v"(x));
  return r;
}

#define AS1 __attribute__((address_space(1)))
#define AS3 __attribute__((address_space(3)))
__device__ __forceinline__ void gload16(const void* g, void* l) {
  __builtin_amdgcn_global_load_lds((AS1 void*)g, (AS3 void*)l, 16, 0, 0);
}

#define MFMA16(a, b, c) __builtin_amdgcn_mfma_f32_16x16x32_bf16(a, b, c, 0, 0, 0)
#define MFMA32(a, b, c) __builtin_amdgcn_mfma_f32_32x32x16_bf16(a, b, c, 0, 0, 0)

// ---------------- f32 -> bf16 convert: x (4 parts of 1M) + 4 weight mats ----
__global__ __launch_bounds__(256) void convert_k(
    const float* __restrict__ x, const float* __restrict__ wq, const float* __restrict__ wk,
    const float* __restrict__ wv, const float* __restrict__ wo,
    u16* __restrict__ xb, u16* __restrict__ wqb, u16* __restrict__ wkb,
    u16* __restrict__ wvb, u16* __restrict__ wob) {
  int part = blockIdx.y;
  const float* src;
  u16* dst;
  size_t base = 0;
  if (part < 4) { src = x; dst = xb; base = (size_t)part << 20; }
  else if (part == 4) { src = wq; dst = wqb; }
  else if (part == 5) { src = wk; dst = wkb; }
  else if (part == 6) { src = wv; dst = wvb; }
  else { src = wo; dst = wob; }
  size_t i = base + ((size_t)(blockIdx.x * 256 + threadIdx.x)) * 4;
  float4 v = *(const float4*)(src + i);
  ushort4 o;
  o.x = f2bf(v.x); o.y = f2bf(v.y); o.z = f2bf(v.z); o.w = f2bf(v.w);
  *(ushort4*)(dst + i) = o;
}

// ---------------- shared 128x128 bf16 GEMM core, C = A * B^T ----------------
// T2 XOR-swizzled LDS (pre-swizzled global source chunk + swizzled ds_read;
// same involution both sides) kills the 16-way b128 row-stride conflict.
template <bool SWAP>
__device__ __forceinline__ void gemm_core(const u16* __restrict__ A,
                                          const u16* __restrict__ Bm,
                                          int m0, int n0, int t,
                                          u16* As, u16* Bs, f32x4 (&acc)[4][4]) {
  int w = t >> 6, lane = t & 63, lr = lane >> 4, lc = lane & 15;
  int wr = w >> 1, wc = w & 1;
  int srow = t >> 3;
  int scolb = ((t & 7) ^ (srow & 7)) * 16;  // swizzled source chunk (bytes)
  int swa = lc & 7;
  const char* Ag = (const char*)A;
  const char* Bg = (const char*)Bm;
  for (int k0 = 0; k0 < DMODEL; k0 += 64) {
#pragma unroll
    for (int i = 0; i < 4; i++) {
      gload16(Ag + ((size_t)(m0 + srow + i * 32) * DMODEL + k0) * 2 + scolb,
              (char*)As + i * 4096 + w * 1024);
      gload16(Bg + ((size_t)(n0 + srow + i * 32) * DMODEL + k0) * 2 + scolb,
              (char*)Bs + i * 4096 + w * 1024);
    }
    __syncthreads();
#pragma unroll
    for (int kk = 0; kk < 2; kk++) {
      bf16x8 af[4], bfr[4];
#pragma unroll
      for (int mi = 0; mi < 4; mi++) {
        int ra = wr * 64 + mi * 16 + lc;
        af[mi] = *(const bf16x8*)((const char*)As + ra * 128 + (((kk * 4 + lr) ^ swa) << 4));
      }
#pragma unroll
      for (int ni = 0; ni < 4; ni++) {
        int rb = wc * 64 + ni * 16 + lc;
        bfr[ni] = *(const bf16x8*)((const char*)Bs + rb * 128 + (((kk * 4 + lr) ^ swa) << 4));
      }
#pragma unroll
      for (int mi = 0; mi < 4; mi++)
#pragma unroll
        for (int ni = 0; ni < 4; ni++) {
          if constexpr (SWAP)
            acc[mi][ni] = MFMA16(bfr[ni], af[mi], acc[mi][ni]);
          else
            acc[mi][ni] = MFMA16(af[mi], bfr[ni], acc[mi][ni]);
        }
    }
    __syncthreads();
  }
}

// ---------------- fused QKV projection: one dispatch, z in {0:Q,1:K,2:VT} ---
__global__ __launch_bounds__(256) void gemm_qkv(
    const u16* __restrict__ A, const u16* __restrict__ wq, const u16* __restrict__ wk,
    const u16* __restrict__ wv, u16* __restrict__ Qb, u16* __restrict__ Kb,
    u16* __restrict__ VTb, const int* __restrict__ pos) {
  __shared__ alignas(16) u16 As[128 * 64];
  __shared__ alignas(16) u16 Bs[128 * 64];
  int z = blockIdx.z;
  int m0 = blockIdx.x * 128, n0 = blockIdx.y * 128;
  int t = threadIdx.x;
  int w = t >> 6, lane = t & 63, lr = lane >> 4, lc = lane & 15;
  int wr = w >> 1, wc = w & 1;
  f32x4 acc[4][4] = {};
  if (z == 2) {
    gemm_core<false>(A, wv, m0, n0, t, As, Bs, acc);
    // normal frag: d = ni*16+lc, s = m0+wr*64+mi*16+lr*4+{0..3}
    int bh = (m0 >> 11) * NHEADS + (n0 >> 6) + wc;
    int scol = (m0 & 2047) + wr * 64;
#pragma unroll
    for (int mi = 0; mi < 4; mi++)
#pragma unroll
      for (int ni = 0; ni < 4; ni++) {
        int d = ni * 16 + lc;
        f32x4 a = acc[mi][ni];
        uint2 pk;
        pk.x = cvtpk(a[0], a[1]);
        pk.y = cvtpk(a[2], a[3]);
        *(uint2*)(VTb + ((size_t)bh * DHEAD + d) * S_LEN + scol + mi * 16 + lr * 4) = pk;
      }
  } else {
    gemm_core<true>(A, z ? wk : wq, m0, n0, t, As, Bs, acc);
    // swapped frag: s = ...+lc, d = ni*16+lr*4+{0..3} = 2 rope pairs
    u16* Oh = z ? Kb : Qb;
    float oscale = z ? 1.0f : 0.125f;  // fold 1/sqrt(DK) into Q
    int h = (n0 >> 6) + wc;
    float fr0[4], fr1[4];
#pragma unroll
    for (int ni = 0; ni < 4; ni++) {
      int i0 = ni * 8 + lr * 2;  // pair index = d/2
      fr0[ni] = exp2f(-0.4152410118407687f * (float)i0);
      fr1[ni] = exp2f(-0.4152410118407687f * (float)(i0 + 1));
    }
#pragma unroll
    for (int mi = 0; mi < 4; mi++) {
      int sg = m0 + wr * 64 + mi * 16 + lc;
      float p = (float)pos[sg];
      int b = sg >> 11, s = sg & 2047;
      u16* dst = Oh + ((size_t)((b * NHEADS + h) * S_LEN + s)) * DHEAD;
#pragma unroll
      for (int ni = 0; ni < 4; ni++) {
        float sn0, cs0, sn1, cs1;
        __sincosf(p * fr0[ni], &sn0, &cs0);
        __sincosf(p * fr1[ni], &sn1, &cs1);
        f32x4 a = acc[mi][ni];
        uint2 pk;
        pk.x = cvtpk((a[0] * cs0 - a[1] * sn0) * oscale,
                     (a[0] * sn0 + a[1] * cs0) * oscale);
        pk.y = cvtpk((a[2] * cs1 - a[3] * sn1) * oscale,
                     (a[2] * sn1 + a[3] * cs1) * oscale);
        *(uint2*)(dst + ni * 16 + lr * 4) = pk;
      }
    }
  }
}

// ---------------- output projection: f32 [M][N], swapped acc -> float4 -----
__global__ __launch_bounds__(256) void gemm_out(const u16* __restrict__ A,
                                                const u16* __restrict__ wo,
                                                float* __restrict__ Of) {
  __shared__ alignas(16) u16 As[128 * 64];
  __shared__ alignas(16) u16 Bs[128 * 64];
  int m0 = blockIdx.x * 128, n0 = blockIdx.y * 128;
  int t = threadIdx.x;
  int w = t >> 6, lane = t & 63, lr = lane >> 4, lc = lane & 15;
  int wr = w >> 1, wc = w & 1;
  f32x4 acc[4][4] = {};
  gemm_core<true>(A, wo, m0, n0, t, As, Bs, acc);
#pragma unroll
  for (int mi = 0; mi < 4; mi++) {
    int m = m0 + wr * 64 + mi * 16 + lc;
#pragma unroll
    for (int ni = 0; ni < 4; ni++) {
      int n = n0 + wc * 64 + ni * 16 + lr * 4;
      *(f32x4*)(Of + (size_t)m * DMODEL + n) = acc[mi][ni];
    }
  }
}

// ---------------- causal flash attention, v12: 4 gangs/CU -------------------
// Gang-count series: 1 gang (R11, 55.8us) < 2 gangs (R10, 50.4us) < 4 (this).
// 128-thread blocks (2 waves x 32 q-rows = 64 q-rows), grid (32,32) = 1024
// blocks = 4/CU (32KB LDS, ~100 VGPR both allow 4). Single-buffered
// KVBLK=128 stage; exposed load latency covered by the other 3 gangs.
// Balanced qt map: CU's 4 blocks get qt {31-j, 16+j, 15-j, j} -> stage-sum
// ~const 35. bh fastest (XCD pinning); heavy group (g=0) dispatched first.
struct AttnSt {
  f32x16 oacc[2];
  float mrun, lrun;
};

__device__ __forceinline__ void attn_tile64(
    const char* kbuf, const char* vbuf, int tb, int kv0, bool domask,
    const bf16x8 (&qf)[4], int qrow, int h, int ql, AttnSt& st) {
  const float L2E = 1.4426950408889634f;
  int swz = ql & 7;
  // S^T = K * Q^T
  f32x16 sacc[2] = {};
  __builtin_amdgcn_s_setprio(1);
#pragma unroll
  for (int kt = 0; kt < 4; kt++) {
    int c = ((2 * kt + h) ^ swz) << 4;
    const char* kr = kbuf + (size_t)tb * 8192;
    bf16x8 k0 = *(const bf16x8*)(kr + ql * 128 + c);
    bf16x8 k1 = *(const bf16x8*)(kr + (32 + ql) * 128 + c);
    sacc[0] = MFMA32(k0, qf[kt], sacc[0]);
    sacc[1] = MFMA32(k1, qf[kt], sacc[1]);
  }
  __builtin_amdgcn_s_setprio(0);
  if (domask) {
#pragma unroll
    for (int r = 0; r < 16; r++) {
      int kvb = kv0 + (r & 3) + 8 * (r >> 2) + 4 * h;
      if (kvb > qrow) sacc[0][r] = -1e30f;
      if (kvb + 32 > qrow) sacc[1][r] = -1e30f;
    }
  }
  // row max: in-register tree + cross-half shfl
  float t8[8];
#pragma unroll
  for (int r = 0; r < 8; r++)
    t8[r] = fmaxf(fmaxf(sacc[0][r], sacc[0][r + 8]), fmaxf(sacc[1][r], sacc[1][r + 8]));
  float t4a = fmaxf(t8[0], t8[4]), t4b = fmaxf(t8[1], t8[5]);
  float t4c = fmaxf(t8[2], t8[6]), t4d = fmaxf(t8[3], t8[7]);
  float mx = fmaxf(fmaxf(t4a, t4b), fmaxf(t4c, t4d));
  mx = fmaxf(mx, __shfl_xor(mx, 32));
  bool up = mx > st.mrun + 5.5451774444795624f;  // defer-max, THR=8*ln2
  if (__any(up)) {
    float newm = up ? mx : st.mrun;
    float scl = fexp2((st.mrun - newm) * L2E);
    st.mrun = newm;
    st.lrun *= scl;
#pragma unroll
    for (int r = 0; r < 16; r++) { st.oacc[0][r] *= scl; st.oacc[1][r] *= scl; }
  }
  float nm2 = -st.mrun * L2E;
#pragma unroll
  for (int r = 0; r < 16; r++) {
    sacc[0][r] = fexp2(__builtin_fmaf(sacc[0][r], L2E, nm2));
    sacc[1][r] = fexp2(__builtin_fmaf(sacc[1][r], L2E, nm2));
  }
  float u8[8];
#pragma unroll
  for (int r = 0; r < 8; r++)
    u8[r] = (sacc[0][r] + sacc[0][r + 8]) + (sacc[1][r] + sacc[1][r + 8]);
  st.lrun += ((u8[0] + u8[4]) + (u8[1] + u8[5])) + ((u8[2] + u8[6]) + (u8[3] + u8[7]));
  // P^T -> bf16 B-frags
  u32x4 pa[4];
#pragma unroll
  for (int tau = 0; tau < 2; tau++) {
    u32x2 rA = plswap2(cvtpk(sacc[tau][0], sacc[tau][1]), cvtpk(sacc[tau][4], sacc[tau][5]));
    pa[2 * tau][0] = rA[0]; pa[2 * tau][2] = rA[1];
    u32x2 rC = plswap2(cvtpk(sacc[tau][2], sacc[tau][3]), cvtpk(sacc[tau][6], sacc[tau][7]));
    pa[2 * tau][1] = rC[0]; pa[2 * tau][3] = rC[1];
    u32x2 rA1 = plswap2(cvtpk(sacc[tau][8], sacc[tau][9]), cvtpk(sacc[tau][12], sacc[tau][13]));
    pa[2 * tau + 1][0] = rA1[0]; pa[2 * tau + 1][2] = rA1[1];
    u32x2 rC1 = plswap2(cvtpk(sacc[tau][10], sacc[tau][11]), cvtpk(sacc[tau][14], sacc[tau][15]));
    pa[2 * tau + 1][1] = rC1[0]; pa[2 * tau + 1][3] = rC1[1];
  }
  // O^T += V^T * P^T
  __builtin_amdgcn_s_setprio(1);
#pragma unroll
  for (int kt = 0; kt < 4; kt++) {
    int c = (tb * 8 + ((2 * kt + h) ^ swz)) << 4;
    bf16x8 v0 = *(const bf16x8*)(vbuf + ql * 256 + c);
    bf16x8 v1 = *(const bf16x8*)(vbuf + (32 + ql) * 256 + c);
    bf16x8 pb = __builtin_bit_cast(bf16x8, pa[kt]);
    st.oacc[0] = MFMA32(v0, pb, st.oacc[0]);
    st.oacc[1] = MFMA32(v1, pb, st.oacc[1]);
  }
  __builtin_amdgcn_s_setprio(0);
}

__global__ __launch_bounds__(128) void attn_k(const u16* __restrict__ Q,
                                              const u16* __restrict__ K,
                                              const u16* __restrict__ VT,
                                              u16* __restrict__ O) {
  __shared__ alignas(16) u16 Ks[128 * 64];  // [kv][d], swizzled, 16KB
  __shared__ alignas(16) u16 Vs[64 * 128];  // [d][kv], swizzled, 16KB
  int bh = blockIdx.x;  // fast dim -> bh%8 tracks XCD
  int y = blockIdx.y;   // 0..31
  int g = y >> 3, j = y & 7;
  int qt = (g == 0) ? (31 - j) : ((g == 1) ? (16 + j) : ((g == 2) ? (15 - j) : j));
  int t = threadIdx.x, w = t >> 6, lane = t & 63;
  int ql = lane & 31, h = lane >> 5;
  size_t base = (size_t)bh * (S_LEN * DHEAD);
  int qrow = qt * 64 + w * 32 + ql;
  bf16x8 qf[4];
#pragma unroll
  for (int kt = 0; kt < 4; kt++)
    qf[kt] = *(const bf16x8*)(Q + base + (size_t)qrow * DHEAD + kt * 16 + h * 8);
  AttnSt st;
  st.oacc[0] = f32x16{};
  st.oacc[1] = f32x16{};
  st.mrun = -1e30f;
  st.lrun = 0.0f;
  // staging source pointers (pre-swizzled global chunks; LDS dest is linear,
  // dest byte = t*16 + p*2048 -> wave-uniform base p*2048 + w*1024 + lane*16)
  int krow = t >> 3;                      // K rows: krow + p*16
  int kc = ((t & 7) ^ (krow & 7)) << 3;   // u16 units
  const u16* Kg0 = K + base + (size_t)krow * DHEAD + kc;
  int vrow = t >> 4;                      // V rows: vrow + p*8
  int vc = ((t & 15) ^ (vrow & 7)) << 3;  // u16 units
  const u16* Vg0 = VT + (size_t)bh * DHEAD * S_LEN + (size_t)vrow * S_LEN + vc;
  char* klb = (char*)&Ks[0] + w * 1024;
  char* vlb = (char*)&Vs[0] + w * 1024;

#define STAGE(s)                                                        \
  do {                                                                  \
    int kv0s = (s) * 128;                                               \
    _Pragma("unroll")                                                   \
    for (int p = 0; p < 8; p++)                                         \
      gload16(Kg0 + (size_t)(kv0s + p * 16) * DHEAD, klb + p * 2048);   \
    _Pragma("unroll")                                                   \
    for (int p = 0; p < 8; p++)                                         \
      gload16(Vg0 + (size_t)(p * 8) * S_LEN + kv0s, vlb + p * 2048);    \
  } while (0)

  int slast = qt >> 1;
  bool evenq = !(qt & 1);
#pragma unroll 1
  for (int s = 0; s <= slast; ++s) {
    STAGE(s);
    asm volatile("s_waitcnt vmcnt(0)" ::: "memory");
    __builtin_amdgcn_s_barrier();
    asm volatile("" ::: "memory");
    const char* kb = (const char*)&Ks[0];
    const char* vb = (const char*)&Vs[0];
    bool diag = (s == slast);
    // tile a: kv [128s, 128s+64)
    attn_tile64(kb, vb, 0, s * 128, diag && evenq, qf, qrow, h, ql, st);
    // tile b: kv [128s+64, 128s+128); diag+even -> entirely above q rows, skip
    if (!(diag && evenq))
      attn_tile64(kb, vb, 1, s * 128 + 64, diag, qf, qrow, h, ql, st);
    asm volatile("s_waitcnt lgkmcnt(0)" ::: "memory");
    __builtin_amdgcn_s_barrier();
    asm volatile("" ::: "memory");
  }
#undef STAGE
  // combine cross-half row-sum, normalize, packed stores
  float lsum = st.lrun + __shfl_xor(st.lrun, 32);
  float inv = 1.0f / lsum;
  int b = bh >> 4, hd = bh & 15;
  u16* Orow = O + ((size_t)(b * S_LEN + qrow)) * DMODEL + hd * 64;
#pragma unroll
  for (int dt = 0; dt < 2; dt++)
#pragma unroll
    for (int rr = 0; rr < 4; rr++) {
      uint2 pk;
      pk.x = cvtpk(st.oacc[dt][4 * rr + 0] * inv, st.oacc[dt][4 * rr + 1] * inv);
      pk.y = cvtpk(st.oacc[dt][4 * rr + 2] * inv, st.oacc[dt][4 * rr + 3] * inv);
      *(uint2*)(Orow + 32 * dt + 8 * rr + 4 * h) = pk;
    }
}

// ---------------- launch -----------------------------------------------------
extern "C" void kernel_launch(void* const* d_in, const int* in_sizes, int n_in,
                              void* d_out, int out_size, void* d_ws, size_t ws_size,
                              hipStream_t stream) {
  (void)in_sizes; (void)n_in; (void)out_size; (void)ws_size;
  const float* x = (const float*)d_in[0];
  const int* tpos = (const int*)d_in[1];
  const float* Wq = (const float*)d_in[2];
  const float* Wk = (const float*)d_in[3];
  const float* Wv = (const float*)d_in[4];
  const float* Wo = (const float*)d_in[5];
  char* ws = (char*)d_ws;
  // workspace map (48 MB used of 56)
  u16* xb  = (u16*)(ws + ((size_t)0 << 20));   // 8 MB  [4096][1024] bf16
  u16* wqb = (u16*)(ws + ((size_t)8 << 20));   // 2 MB
  u16* wkb = (u16*)(ws + ((size_t)10 << 20));  // 2 MB
  u16* wvb = (u16*)(ws + ((size_t)12 << 20));  // 2 MB
  u16* wob = (u16*)(ws + ((size_t)14 << 20));  // 2 MB
  u16* Qb  = (u16*)(ws + ((size_t)16 << 20));  // 8 MB  [B,H,S,DK] (rope'd, scaled)
  u16* Kb  = (u16*)(ws + ((size_t)24 << 20));  // 8 MB  [B,H,S,DK] (rope'd)
  u16* VTb = (u16*)(ws + ((size_t)32 << 20));  // 8 MB  [B,H,DK,S]
  u16* Ob  = (u16*)(ws + ((size_t)40 << 20));  // 8 MB  [B,S,DMODEL] bf16

  convert_k<<<dim3(1024, 8), 256, 0, stream>>>(x, Wq, Wk, Wv, Wo, xb, wqb, wkb, wvb, wob);
  gemm_qkv<<<dim3(32, 8, 3), 256, 0, stream>>>(xb, wqb, wkb, wvb, Qb, Kb, VTb, tpos);
  attn_k<<<dim3(32, 32), 128, 0, stream>>>(Qb, Kb, VTb, Ob);
  gemm_out<<<dim3(32, 8), 256, 0, stream>>>(Ob, wob, (float*)d_out);
}

// Round 13
// 122.127 us; speedup vs baseline: 1.0975x; 1.0052x over previous
//
#include <hip/hip_runtime.h>
#include <stdint.h>

#define S_LEN 2048
#define NHEADS 16
#define DHEAD 64
#define DMODEL 1024

typedef unsigned short u16;
typedef unsigned int u32;
typedef __bf16 bf16x8 __attribute__((ext_vector_type(8)));
typedef float f32x4 __attribute__((ext_vector_type(4)));
typedef float f32x16 __attribute__((ext_vector_type(16)));
typedef u32 u32x4 __attribute__((ext_vector_type(4)));
typedef u32 u32x2 __attribute__((ext_vector_type(2)));

__device__ __forceinline__ float bf2f(u16 u) {
  u32 x = ((u32)u) << 16;
  float f;
  __builtin_memcpy(&f, &x, 4);
  return f;
}
__device__ __forceinline__ u16 f2bf(float f) {
  u32 x;
  __builtin_memcpy(&x, &f, 4);
  x += 0x7FFFu + ((x >> 16) & 1u);
  return (u16)(x >> 16);
}
// packed f32 pair -> bf16 pair (lo = a, hi = b)
__device__ __forceinline__ u32 cvtpk(float a, float b) {
  u32 r;
  asm("v_cvt_pk_bf16_f32 %0, %1, %2" : "=v"(r) : "v"(a), "v"(b));
  return r;
}
// r[0] = {a_lo, b_lo}, r[1] = {a_hi, b_hi}
__device__ __forceinline__ u32x2 plswap2(u32 a, u32 b) {
  return __builtin_amdgcn_permlane32_swap(a, b, false, false);
}
// single-instruction exp2
__device__ __forceinline__ float fexp2(float x) {
  float r;
  asm("v_exp_f32 %0, %1" : "=v"(r) : "v"(x));
  return r;
}

#define AS1 __attribute__((address_space(1)))
#define AS3 __attribute__((address_space(3)))
__device__ __forceinline__ void gload16(const void* g, void* l) {
  __builtin_amdgcn_global_load_lds((AS1 void*)g, (AS3 void*)l, 16, 0, 0);
}

#define MFMA16(a, b, c) __builtin_amdgcn_mfma_f32_16x16x32_bf16(a, b, c, 0, 0, 0)
#define MFMA32(a, b, c) __builtin_amdgcn_mfma_f32_32x32x16_bf16(a, b, c, 0, 0, 0)

// ---------------- f32 -> bf16 convert: x (4 parts of 1M) + 4 weight mats ----
__global__ __launch_bounds__(256) void convert_k(
    const float* __restrict__ x, const float* __restrict__ wq, const float* __restrict__ wk,
    const float* __restrict__ wv, const float* __restrict__ wo,
    u16* __restrict__ xb, u16* __restrict__ wqb, u16* __restrict__ wkb,
    u16* __restrict__ wvb, u16* __restrict__ wob) {
  int part = blockIdx.y;
  const float* src;
  u16* dst;
  size_t base = 0;
  if (part < 4) { src = x; dst = xb; base = (size_t)part << 20; }
  else if (part == 4) { src = wq; dst = wqb; }
  else if (part == 5) { src = wk; dst = wkb; }
  else if (part == 6) { src = wv; dst = wvb; }
  else { src = wo; dst = wob; }
  size_t i = base + ((size_t)(blockIdx.x * 256 + threadIdx.x)) * 4;
  float4 v = *(const float4*)(src + i);
  ushort4 o;
  o.x = f2bf(v.x); o.y = f2bf(v.y); o.z = f2bf(v.z); o.w = f2bf(v.w);
  *(ushort4*)(dst + i) = o;
}

// ---------------- shared 128x128 bf16 GEMM core, C = A * B^T ----------------
// T2 XOR-swizzled LDS (pre-swizzled global source chunk + swizzled ds_read).
template <bool SWAP>
__device__ __forceinline__ void gemm_core(const u16* __restrict__ A,
                                          const u16* __restrict__ Bm,
                                          int m0, int n0, int t,
                                          u16* As, u16* Bs, f32x4 (&acc)[4][4]) {
  int w = t >> 6, lane = t & 63, lr = lane >> 4, lc = lane & 15;
  int wr = w >> 1, wc = w & 1;
  int srow = t >> 3;
  int scolb = ((t & 7) ^ (srow & 7)) * 16;  // swizzled source chunk (bytes)
  int swa = lc & 7;
  const char* Ag = (const char*)A;
  const char* Bg = (const char*)Bm;
  for (int k0 = 0; k0 < DMODEL; k0 += 64) {
#pragma unroll
    for (int i = 0; i < 4; i++) {
      gload16(Ag + ((size_t)(m0 + srow + i * 32) * DMODEL + k0) * 2 + scolb,
              (char*)As + i * 4096 + w * 1024);
      gload16(Bg + ((size_t)(n0 + srow + i * 32) * DMODEL + k0) * 2 + scolb,
              (char*)Bs + i * 4096 + w * 1024);
    }
    __syncthreads();
#pragma unroll
    for (int kk = 0; kk < 2; kk++) {
      bf16x8 af[4], bfr[4];
#pragma unroll
      for (int mi = 0; mi < 4; mi++) {
        int ra = wr * 64 + mi * 16 + lc;
        af[mi] = *(const bf16x8*)((const char*)As + ra * 128 + (((kk * 4 + lr) ^ swa) << 4));
      }
#pragma unroll
      for (int ni = 0; ni < 4; ni++) {
        int rb = wc * 64 + ni * 16 + lc;
        bfr[ni] = *(const bf16x8*)((const char*)Bs + rb * 128 + (((kk * 4 + lr) ^ swa) << 4));
      }
#pragma unroll
      for (int mi = 0; mi < 4; mi++)
#pragma unroll
        for (int ni = 0; ni < 4; ni++) {
          if constexpr (SWAP)
            acc[mi][ni] = MFMA16(bfr[ni], af[mi], acc[mi][ni]);
          else
            acc[mi][ni] = MFMA16(af[mi], bfr[ni], acc[mi][ni]);
        }
    }
    __syncthreads();
  }
}

// ---------------- fused QKV projection: one dispatch, z in {0:Q,1:K,2:VT} ---
__global__ __launch_bounds__(256) void gemm_qkv(
    const u16* __restrict__ A, const u16* __restrict__ wq, const u16* __restrict__ wk,
    const u16* __restrict__ wv, u16* __restrict__ Qb, u16* __restrict__ Kb,
    u16* __restrict__ VTb, const int* __restrict__ pos) {
  __shared__ alignas(16) u16 As[128 * 64];
  __shared__ alignas(16) u16 Bs[128 * 64];
  int z = blockIdx.z;
  int m0 = blockIdx.x * 128, n0 = blockIdx.y * 128;
  int t = threadIdx.x;
  int w = t >> 6, lane = t & 63, lr = lane >> 4, lc = lane & 15;
  int wr = w >> 1, wc = w & 1;
  f32x4 acc[4][4] = {};
  if (z == 2) {
    gemm_core<false>(A, wv, m0, n0, t, As, Bs, acc);
    // normal frag: d = ni*16+lc, s = m0+wr*64+mi*16+lr*4+{0..3}
    int bh = (m0 >> 11) * NHEADS + (n0 >> 6) + wc;
    int scol = (m0 & 2047) + wr * 64;
#pragma unroll
    for (int mi = 0; mi < 4; mi++)
#pragma unroll
      for (int ni = 0; ni < 4; ni++) {
        int d = ni * 16 + lc;
        f32x4 a = acc[mi][ni];
        uint2 pk;
        pk.x = cvtpk(a[0], a[1]);
        pk.y = cvtpk(a[2], a[3]);
        *(uint2*)(VTb + ((size_t)bh * DHEAD + d) * S_LEN + scol + mi * 16 + lr * 4) = pk;
      }
  } else {
    gemm_core<true>(A, z ? wk : wq, m0, n0, t, As, Bs, acc);
    // swapped frag: s = ...+lc, d = ni*16+lr*4+{0..3} = 2 rope pairs
    u16* Oh = z ? Kb : Qb;
    float oscale = z ? 1.0f : 0.125f;  // fold 1/sqrt(DK) into Q
    int h = (n0 >> 6) + wc;
    float fr0[4], fr1[4];
#pragma unroll
    for (int ni = 0; ni < 4; ni++) {
      int i0 = ni * 8 + lr * 2;  // pair index = d/2
      fr0[ni] = exp2f(-0.4152410118407687f * (float)i0);
      fr1[ni] = exp2f(-0.4152410118407687f * (float)(i0 + 1));
    }
#pragma unroll
    for (int mi = 0; mi < 4; mi++) {
      int sg = m0 + wr * 64 + mi * 16 + lc;
      float p = (float)pos[sg];
      int b = sg >> 11, s = sg & 2047;
      u16* dst = Oh + ((size_t)((b * NHEADS + h) * S_LEN + s)) * DHEAD;
#pragma unroll
      for (int ni = 0; ni < 4; ni++) {
        float sn0, cs0, sn1, cs1;
        __sincosf(p * fr0[ni], &sn0, &cs0);
        __sincosf(p * fr1[ni], &sn1, &cs1);
        f32x4 a = acc[mi][ni];
        uint2 pk;
        pk.x = cvtpk((a[0] * cs0 - a[1] * sn0) * oscale,
                     (a[0] * sn0 + a[1] * cs0) * oscale);
        pk.y = cvtpk((a[2] * cs1 - a[3] * sn1) * oscale,
                     (a[2] * sn1 + a[3] * cs1) * oscale);
        *(uint2*)(dst + ni * 16 + lr * 4) = pk;
      }
    }
  }
}

// ---------------- output projection: f32 [M][N], swapped acc -> float4 -----
__global__ __launch_bounds__(256) void gemm_out(const u16* __restrict__ A,
                                                const u16* __restrict__ wo,
                                                float* __restrict__ Of) {
  __shared__ alignas(16) u16 As[128 * 64];
  __shared__ alignas(16) u16 Bs[128 * 64];
  int m0 = blockIdx.x * 128, n0 = blockIdx.y * 128;
  int t = threadIdx.x;
  int w = t >> 6, lane = t & 63, lr = lane >> 4, lc = lane & 15;
  int wr = w >> 1, wc = w & 1;
  f32x4 acc[4][4] = {};
  gemm_core<true>(A, wo, m0, n0, t, As, Bs, acc);
#pragma unroll
  for (int mi = 0; mi < 4; mi++) {
    int m = m0 + wr * 64 + mi * 16 + lc;
#pragma unroll
    for (int ni = 0; ni < 4; ni++) {
      int n = n0 + wc * 64 + ni * 16 + lr * 4;
      *(f32x4*)(Of + (size_t)m * DMODEL + n) = acc[mi][ni];
    }
  }
}

// ---------------- causal flash attention, v13: split-K gang chunks ----------
// R12 counters: makespan tracked the longest (32-tile) q-tile while per-CU
// mean is 16.5 tile-times -> only splitting KV can halve it. Chunk = 8
// KV-tiles (512 kv). Per 64-row q-tile qt: C=ceil((qt+1)/8) chunks -> 2560
// uniform 128-thr blocks (10/CU demand, ~8 resident) -> near-perfect packing.
// Single-buffered 64-kv stage (16KB LDS); proven staged/swizzled body.
// qt<8 direct write; else bf16 partials {O-frag, m, l} merged by merge_k.
struct AttnSt {
  f32x16 oacc[2];
  float mrun, lrun;
};

__device__ __forceinline__ void attn_tile64(
    const char* kbuf, const char* vbuf, int kv0, bool domask,
    const bf16x8 (&qf)[4], int qrow, int h, int ql, AttnSt& st) {
  const float L2E = 1.4426950408889634f;
  int swz = ql & 7;
  // S^T = K * Q^T
  f32x16 sacc[2] = {};
  __builtin_amdgcn_s_setprio(1);
#pragma unroll
  for (int kt = 0; kt < 4; kt++) {
    int c = ((2 * kt + h) ^ swz) << 4;
    bf16x8 k0 = *(const bf16x8*)(kbuf + ql * 128 + c);
    bf16x8 k1 = *(const bf16x8*)(kbuf + (32 + ql) * 128 + c);
    sacc[0] = MFMA32(k0, qf[kt], sacc[0]);
    sacc[1] = MFMA32(k1, qf[kt], sacc[1]);
  }
  __builtin_amdgcn_s_setprio(0);
  if (domask) {
#pragma unroll
    for (int r = 0; r < 16; r++) {
      int kvb = kv0 + (r & 3) + 8 * (r >> 2) + 4 * h;
      if (kvb > qrow) sacc[0][r] = -1e30f;
      if (kvb + 32 > qrow) sacc[1][r] = -1e30f;
    }
  }
  // row max: in-register tree + cross-half shfl
  float t8[8];
#pragma unroll
  for (int r = 0; r < 8; r++)
    t8[r] = fmaxf(fmaxf(sacc[0][r], sacc[0][r + 8]), fmaxf(sacc[1][r], sacc[1][r + 8]));
  float t4a = fmaxf(t8[0], t8[4]), t4b = fmaxf(t8[1], t8[5]);
  float t4c = fmaxf(t8[2], t8[6]), t4d = fmaxf(t8[3], t8[7]);
  float mx = fmaxf(fmaxf(t4a, t4b), fmaxf(t4c, t4d));
  mx = fmaxf(mx, __shfl_xor(mx, 32));
  bool up = mx > st.mrun + 5.5451774444795624f;  // defer-max, THR=8*ln2
  if (__any(up)) {
    float newm = up ? mx : st.mrun;
    float scl = fexp2((st.mrun - newm) * L2E);
    st.mrun = newm;
    st.lrun *= scl;
#pragma unroll
    for (int r = 0; r < 16; r++) { st.oacc[0][r] *= scl; st.oacc[1][r] *= scl; }
  }
  float nm2 = -st.mrun * L2E;
#pragma unroll
  for (int r = 0; r < 16; r++) {
    sacc[0][r] = fexp2(__builtin_fmaf(sacc[0][r], L2E, nm2));
    sacc[1][r] = fexp2(__builtin_fmaf(sacc[1][r], L2E, nm2));
  }
  float u8[8];
#pragma unroll
  for (int r = 0; r < 8; r++)
    u8[r] = (sacc[0][r] + sacc[0][r + 8]) + (sacc[1][r] + sacc[1][r + 8]);
  st.lrun += ((u8[0] + u8[4]) + (u8[1] + u8[5])) + ((u8[2] + u8[6]) + (u8[3] + u8[7]));
  // P^T -> bf16 B-frags
  u32x4 pa[4];
#pragma unroll
  for (int tau = 0; tau < 2; tau++) {
    u32x2 rA = plswap2(cvtpk(sacc[tau][0], sacc[tau][1]), cvtpk(sacc[tau][4], sacc[tau][5]));
    pa[2 * tau][0] = rA[0]; pa[2 * tau][2] = rA[1];
    u32x2 rC = plswap2(cvtpk(sacc[tau][2], sacc[tau][3]), cvtpk(sacc[tau][6], sacc[tau][7]));
    pa[2 * tau][1] = rC[0]; pa[2 * tau][3] = rC[1];
    u32x2 rA1 = plswap2(cvtpk(sacc[tau][8], sacc[tau][9]), cvtpk(sacc[tau][12], sacc[tau][13]));
    pa[2 * tau + 1][0] = rA1[0]; pa[2 * tau + 1][2] = rA1[1];
    u32x2 rC1 = plswap2(cvtpk(sacc[tau][10], sacc[tau][11]), cvtpk(sacc[tau][14], sacc[tau][15]));
    pa[2 * tau + 1][1] = rC1[0]; pa[2 * tau + 1][3] = rC1[1];
  }
  // O^T += V^T * P^T  (V tile [d=64][kv=64], stride 128B)
  __builtin_amdgcn_s_setprio(1);
#pragma unroll
  for (int kt = 0; kt < 4; kt++) {
    int c = ((2 * kt + h) ^ swz) << 4;
    bf16x8 v0 = *(const bf16x8*)(vbuf + ql * 128 + c);
    bf16x8 v1 = *(const bf16x8*)(vbuf + (32 + ql) * 128 + c);
    bf16x8 pb = __builtin_bit_cast(bf16x8, pa[kt]);
    st.oacc[0] = MFMA32(v0, pb, st.oacc[0]);
    st.oacc[1] = MFMA32(v1, pb, st.oacc[1]);
  }
  __builtin_amdgcn_s_setprio(0);
}

__device__ __forceinline__ void attn_store(const AttnSt& st, float lsum,
                                           u16* __restrict__ O, int bh, int qrow, int h) {
  float inv = 1.0f / lsum;
  int b = bh >> 4, hd = bh & 15;
  u16* Orow = O + ((size_t)(b * S_LEN + qrow)) * DMODEL + hd * 64;
#pragma unroll
  for (int dt = 0; dt < 2; dt++)
#pragma unroll
    for (int rr = 0; rr < 4; rr++) {
      uint2 pk;
      pk.x = cvtpk(st.oacc[dt][4 * rr + 0] * inv, st.oacc[dt][4 * rr + 1] * inv);
      pk.y = cvtpk(st.oacc[dt][4 * rr + 2] * inv, st.oacc[dt][4 * rr + 3] * inv);
      *(uint2*)(Orow + 32 * dt + 8 * rr + 4 * h) = pk;
    }
}

__global__ __launch_bounds__(128, 4) void attn_k(const u16* __restrict__ Q,
                                                 const u16* __restrict__ K,
                                                 const u16* __restrict__ VT,
                                                 u16* __restrict__ O,
                                                 char* __restrict__ PB) {
  __shared__ alignas(16) u16 Ks[64 * 64];  // [kv][d], swizzled, 8KB
  __shared__ alignas(16) u16 Vs[64 * 64];  // [d][kv], swizzled, 8KB
  int bh = blockIdx.x;  // fast dim -> bh%8 tracks XCD
  int y = blockIdx.y;   // 0..79: chunk map, heavy q-tiles first
  int qt, c;
  if (y < 32) { qt = 24 + (y & 7); c = y >> 3; }
  else if (y < 56) { int u = y - 32; qt = 16 + (u & 7); c = u >> 3; }
  else if (y < 72) { int u = y - 56; qt = 8 + (u & 7); c = u >> 3; }
  else { qt = y - 72; c = 0; }
  int nt0 = c * 8;
  int nt1 = (nt0 + 7 < qt) ? (nt0 + 7) : qt;  // tiles clipped at diagonal
  bool partial = (qt >= 8);
  int t = threadIdx.x, w = t >> 6, lane = t & 63;
  int ql = lane & 31, h = lane >> 5;
  size_t base = (size_t)bh * (S_LEN * DHEAD);
  int qrow = qt * 64 + w * 32 + ql;
  bf16x8 qf[4];
#pragma unroll
  for (int kt = 0; kt < 4; kt++)
    qf[kt] = *(const bf16x8*)(Q + base + (size_t)qrow * DHEAD + kt * 16 + h * 8);
  AttnSt st;
  st.oacc[0] = f32x16{};
  st.oacc[1] = f32x16{};
  st.mrun = -1e30f;
  st.lrun = 0.0f;
  // staging source (pre-swizzled global chunks; LDS dest linear t*16 + p*2048)
  int srow = t >> 3;                     // 0..15
  int sc = ((t & 7) ^ (srow & 7)) << 3;  // u16 units
  const u16* Kg0 = K + base + (size_t)srow * DHEAD + sc;
  const u16* Vg0 = VT + (size_t)bh * DHEAD * S_LEN + (size_t)srow * S_LEN + sc;
  char* kl = (char*)Ks + w * 1024;
  char* vl = (char*)Vs + w * 1024;
#pragma unroll 1
  for (int s = nt0; s <= nt1; ++s) {
#pragma unroll
    for (int p = 0; p < 4; p++)
      gload16(Kg0 + (size_t)(s * 64 + p * 16) * DHEAD, kl + p * 2048);
#pragma unroll
    for (int p = 0; p < 4; p++)
      gload16(Vg0 + (size_t)(p * 16) * S_LEN + s * 64, vl + p * 2048);
    asm volatile("s_waitcnt vmcnt(0)" ::: "memory");
    __builtin_amdgcn_s_barrier();
    asm volatile("" ::: "memory");
    attn_tile64((const char*)Ks, (const char*)Vs, s * 64, s == qt, qf, qrow, h, ql, st);
    asm volatile("s_waitcnt lgkmcnt(0)" ::: "memory");
    __builtin_amdgcn_s_barrier();
    asm volatile("" ::: "memory");
  }
  float lsum = st.lrun + __shfl_xor(st.lrun, 32);
  if (!partial) {
    attn_store(st, lsum, O, bh, qrow, h);
  } else {
    // slot: qt 8-15: 2 chunks; 16-23: 3; 24-31: 4  (72 slots/bh, 8704B each)
    int off = (qt < 16) ? (qt - 8) * 2 + c
                        : ((qt < 24) ? 16 + (qt - 16) * 3 + c : 40 + (qt - 24) * 4 + c);
    char* pp = PB + (size_t)(bh * 72 + off) * 8704;
    u32x4 wv[4];
#pragma unroll
    for (int dt = 0; dt < 2; dt++)
#pragma unroll
      for (int rr = 0; rr < 4; rr++) {
        int wi = dt * 8 + rr * 2;
        ((u32*)wv)[wi] = cvtpk(st.oacc[dt][4 * rr + 0], st.oacc[dt][4 * rr + 1]);
        ((u32*)wv)[wi + 1] = cvtpk(st.oacc[dt][4 * rr + 2], st.oacc[dt][4 * rr + 3]);
      }
#pragma unroll
    for (int i = 0; i < 4; i++) *(u32x4*)(pp + t * 64 + i * 16) = wv[i];
    if (h == 0) {
      float2 ml;
      ml.x = st.mrun;  // cross-half-combined every tile
      ml.y = lsum;     // combined sum
      *(float2*)(pp + 8192 + (size_t)(w * 32 + ql) * 8) = ml;
    }
  }
}

// ---------------- merge split-K partials (qt >= 8), C in 2..4 ---------------
__global__ __launch_bounds__(128) void merge_k(const char* __restrict__ PB,
                                               u16* __restrict__ O) {
  int bh = blockIdx.x;
  int qt = 8 + blockIdx.y;  // 8..31
  int t = threadIdx.x, w = t >> 6, lane = t & 63;
  int ql = lane & 31, h = lane >> 5;
  int row = w * 32 + ql;
  int C = (qt < 16) ? 2 : ((qt < 24) ? 3 : 4);
  int off = (qt < 16) ? (qt - 8) * 2 : ((qt < 24) ? 16 + (qt - 16) * 3 : 40 + (qt - 24) * 4);
  const char* p = PB + (size_t)(bh * 72 + off) * 8704;
  const float L2E = 1.4426950408889634f;
  float m = -1e30f, l = 0.0f;
  float o[32];
#pragma unroll
  for (int i = 0; i < 32; i++) o[i] = 0.0f;
#pragma unroll 1
  for (int cc = 0; cc < C; ++cc, p += 8704) {
    float2 mlc = *(const float2*)(p + 8192 + (size_t)row * 8);
    float newm = fmaxf(m, mlc.x);
    float s_old = fexp2((m - newm) * L2E);
    float s_new = fexp2((mlc.x - newm) * L2E);
    m = newm;
    l = l * s_old + mlc.y * s_new;
#pragma unroll
    for (int i = 0; i < 16; i++) {
      u32 x = *(const u32*)(p + t * 64 + i * 4);
      o[2 * i] = o[2 * i] * s_old + bf2f((u16)x) * s_new;
      o[2 * i + 1] = o[2 * i + 1] * s_old + bf2f((u16)(x >> 16)) * s_new;
    }
  }
  float inv = 1.0f / l;
  int qrow = qt * 64 + row;
  int b = bh >> 4, hd = bh & 15;
  u16* Orow = O + ((size_t)(b * S_LEN + qrow)) * DMODEL + hd * 64;
#pragma unroll
  for (int dt = 0; dt < 2; dt++)
#pragma unroll
    for (int rr = 0; rr < 4; rr++) {
      int i0 = 2 * (dt * 8 + rr * 2);
      uint2 pk;
      pk.x = cvtpk(o[i0] * inv, o[i0 + 1] * inv);
      pk.y = cvtpk(o[i0 + 2] * inv, o[i0 + 3] * inv);
      *(uint2*)(Orow + 32 * dt + 8 * rr + 4 * h) = pk;
    }
}

// ---------------- launch -----------------------------------------------------
extern "C" void kernel_launch(void* const* d_in, const int* in_sizes, int n_in,
                              void* d_out, int out_size, void* d_ws, size_t ws_size,
                              hipStream_t stream) {
  (void)in_sizes; (void)n_in; (void)out_size; (void)ws_size;
  const float* x = (const float*)d_in[0];
  const int* tpos = (const int*)d_in[1];
  const float* Wq = (const float*)d_in[2];
  const float* Wk = (const float*)d_in[3];
  const float* Wv = (const float*)d_in[4];
  const float* Wo = (const float*)d_in[5];
  char* ws = (char*)d_ws;
  // workspace map (56 MB). PB (20.0 MB attn partials) overlays xb/wq/wk/wv,
  // dead after gemm_qkv. wob lives at +22 until gemm_out.
  u16* xb  = (u16*)(ws + ((size_t)0 << 20));   // 8 MB  (dead after gemm_qkv)
  u16* wqb = (u16*)(ws + ((size_t)8 << 20));   // 2 MB  (dead after gemm_qkv)
  u16* wkb = (u16*)(ws + ((size_t)10 << 20));  // 2 MB  (dead after gemm_qkv)
  u16* wvb = (u16*)(ws + ((size_t)12 << 20));  // 2 MB  (dead after gemm_qkv)
  char* PB = ws;                               // 20.0 MB partials [0,22)
  u16* wob = (u16*)(ws + ((size_t)22 << 20));  // 2 MB
  u16* Qb  = (u16*)(ws + ((size_t)24 << 20));  // 8 MB  [B,H,S,DK] (rope'd, scaled)
  u16* Kb  = (u16*)(ws + ((size_t)32 << 20));  // 8 MB  [B,H,S,DK] (rope'd)
  u16* VTb = (u16*)(ws + ((size_t)40 << 20));  // 8 MB  [B,H,DK,S]
  u16* Ob  = (u16*)(ws + ((size_t)48 << 20));  // 8 MB  [B,S,DMODEL] bf16

  convert_k<<<dim3(1024, 8), 256, 0, stream>>>(x, Wq, Wk, Wv, Wo, xb, wqb, wkb, wvb, wob);
  gemm_qkv<<<dim3(32, 8, 3), 256, 0, stream>>>(xb, wqb, wkb, wvb, Qb, Kb, VTb, tpos);
  attn_k<<<dim3(32, 80), 128, 0, stream>>>(Qb, Kb, VTb, Ob, PB);
  merge_k<<<dim3(32, 24), 128, 0, stream>>>(PB, Ob);
  gemm_out<<<dim3(32, 8), 256, 0, stream>>>(Ob, wob, (float*)d_out);
}

// Round 14
// 117.014 us; speedup vs baseline: 1.1454x; 1.0437x over previous
//
#include <hip/hip_runtime.h>
#include <stdint.h>

#define S_LEN 2048
#define NHEADS 16
#define DHEAD 64
#define DMODEL 1024

typedef unsigned short u16;
typedef unsigned int u32;
typedef __bf16 bf16x8 __attribute__((ext_vector_type(8)));
typedef float f32x4 __attribute__((ext_vector_type(4)));
typedef float f32x16 __attribute__((ext_vector_type(16)));
typedef u32 u32x4 __attribute__((ext_vector_type(4)));
typedef u32 u32x2 __attribute__((ext_vector_type(2)));

__device__ __forceinline__ float bf2f(u16 u) {
  u32 x = ((u32)u) << 16;
  float f;
  __builtin_memcpy(&f, &x, 4);
  return f;
}
__device__ __forceinline__ u16 f2bf(float f) {
  u32 x;
  __builtin_memcpy(&x, &f, 4);
  x += 0x7FFFu + ((x >> 16) & 1u);
  return (u16)(x >> 16);
}
// packed f32 pair -> bf16 pair (lo = a, hi = b)
__device__ __forceinline__ u32 cvtpk(float a, float b) {
  u32 r;
  asm("v_cvt_pk_bf16_f32 %0, %1, %2" : "=v"(r) : "v"(a), "v"(b));
  return r;
}
// r[0] = {a_lo, b_lo}, r[1] = {a_hi, b_hi}
__device__ __forceinline__ u32x2 plswap2(u32 a, u32 b) {
  return __builtin_amdgcn_permlane32_swap(a, b, false, false);
}
// single-instruction exp2
__device__ __forceinline__ float fexp2(float x) {
  float r;
  asm("v_exp_f32 %0, %1" : "=v"(r) : "v"(x));
  return r;
}

#define AS1 __attribute__((address_space(1)))
#define AS3 __attribute__((address_space(3)))
__device__ __forceinline__ void gload16(const void* g, void* l) {
  __builtin_amdgcn_global_load_lds((AS1 void*)g, (AS3 void*)l, 16, 0, 0);
}

#define MFMA16(a, b, c) __builtin_amdgcn_mfma_f32_16x16x32_bf16(a, b, c, 0, 0, 0)
#define MFMA32(a, b, c) __builtin_amdgcn_mfma_f32_32x32x16_bf16(a, b, c, 0, 0, 0)

// ---------------- f32 -> bf16 convert: x (4 parts of 1M) + 4 weight mats ----
__global__ __launch_bounds__(256) void convert_k(
    const float* __restrict__ x, const float* __restrict__ wq, const float* __restrict__ wk,
    const float* __restrict__ wv, const float* __restrict__ wo,
    u16* __restrict__ xb, u16* __restrict__ wqb, u16* __restrict__ wkb,
    u16* __restrict__ wvb, u16* __restrict__ wob) {
  int part = blockIdx.y;
  const float* src;
  u16* dst;
  size_t base = 0;
  if (part < 4) { src = x; dst = xb; base = (size_t)part << 20; }
  else if (part == 4) { src = wq; dst = wqb; }
  else if (part == 5) { src = wk; dst = wkb; }
  else if (part == 6) { src = wv; dst = wvb; }
  else { src = wo; dst = wob; }
  size_t i = base + ((size_t)(blockIdx.x * 256 + threadIdx.x)) * 4;
  float4 v = *(const float4*)(src + i);
  ushort4 o;
  o.x = f2bf(v.x); o.y = f2bf(v.y); o.z = f2bf(v.z); o.w = f2bf(v.w);
  *(ushort4*)(dst + i) = o;
}

// ---------------- shared 128x128 bf16 GEMM core, C = A * B^T ----------------
// v2: true 2-phase (T3+T4 minimum recipe): double-buffered LDS; STAGE(k+1)
// issued BEFORE computing tile k; one vmcnt(0)+barrier per K-step (loads have
// the whole compute phase in flight). T2 XOR-swizzle retained.
template <bool SWAP>
__device__ __forceinline__ void gemm_core(const u16* __restrict__ A,
                                          const u16* __restrict__ Bm,
                                          int m0, int n0, int t,
                                          u16 (&As)[2][128 * 64],
                                          u16 (&Bs)[2][128 * 64],
                                          f32x4 (&acc)[4][4]) {
  int w = t >> 6, lane = t & 63, lr = lane >> 4, lc = lane & 15;
  int wr = w >> 1, wc = w & 1;
  int srow = t >> 3;
  int scolb = ((t & 7) ^ (srow & 7)) * 16;  // swizzled source chunk (bytes)
  int swa = lc & 7;
  const char* Ag = (const char*)A + (size_t)(m0 + srow) * DMODEL * 2 + scolb;
  const char* Bg = (const char*)Bm + (size_t)(n0 + srow) * DMODEL * 2 + scolb;

#define GSTAGE(k0s, buf)                                                 \
  do {                                                                   \
    _Pragma("unroll")                                                    \
    for (int i = 0; i < 4; i++) {                                        \
      gload16(Ag + ((size_t)i * 32 * DMODEL + (k0s)) * 2,                \
              (char*)As[buf] + i * 4096 + w * 1024);                     \
      gload16(Bg + ((size_t)i * 32 * DMODEL + (k0s)) * 2,                \
              (char*)Bs[buf] + i * 4096 + w * 1024);                     \
    }                                                                    \
  } while (0)

  GSTAGE(0, 0);
  asm volatile("s_waitcnt vmcnt(0)" ::: "memory");
  __builtin_amdgcn_s_barrier();
  asm volatile("" ::: "memory");
  int cur = 0;
#pragma unroll 1
  for (int k0 = 0; k0 < DMODEL; k0 += 64) {
    if (k0 + 64 < DMODEL) GSTAGE(k0 + 64, cur ^ 1);  // in flight over compute
    const u16* Ab = As[cur];
    const u16* Bb = Bs[cur];
#pragma unroll
    for (int kk = 0; kk < 2; kk++) {
      bf16x8 af[4], bfr[4];
#pragma unroll
      for (int mi = 0; mi < 4; mi++) {
        int ra = wr * 64 + mi * 16 + lc;
        af[mi] = *(const bf16x8*)((const char*)Ab + ra * 128 + (((kk * 4 + lr) ^ swa) << 4));
      }
#pragma unroll
      for (int ni = 0; ni < 4; ni++) {
        int rb = wc * 64 + ni * 16 + lc;
        bfr[ni] = *(const bf16x8*)((const char*)Bb + rb * 128 + (((kk * 4 + lr) ^ swa) << 4));
      }
#pragma unroll
      for (int mi = 0; mi < 4; mi++)
#pragma unroll
        for (int ni = 0; ni < 4; ni++) {
          if constexpr (SWAP)
            acc[mi][ni] = MFMA16(bfr[ni], af[mi], acc[mi][ni]);
          else
            acc[mi][ni] = MFMA16(af[mi], bfr[ni], acc[mi][ni]);
        }
    }
    asm volatile("s_waitcnt vmcnt(0)" ::: "memory");  // next tile landed
    __builtin_amdgcn_s_barrier();
    asm volatile("" ::: "memory");
    cur ^= 1;
  }
#undef GSTAGE
}

// ---------------- fused QKV projection: one dispatch, z in {0:Q,1:K,2:VT} ---
__global__ __launch_bounds__(256) void gemm_qkv(
    const u16* __restrict__ A, const u16* __restrict__ wq, const u16* __restrict__ wk,
    const u16* __restrict__ wv, u16* __restrict__ Qb, u16* __restrict__ Kb,
    u16* __restrict__ VTb, const int* __restrict__ pos) {
  __shared__ alignas(16) u16 As[2][128 * 64];
  __shared__ alignas(16) u16 Bs[2][128 * 64];
  int z = blockIdx.z;
  int m0 = blockIdx.x * 128, n0 = blockIdx.y * 128;
  int t = threadIdx.x;
  int w = t >> 6, lane = t & 63, lr = lane >> 4, lc = lane & 15;
  int wr = w >> 1, wc = w & 1;
  f32x4 acc[4][4] = {};
  if (z == 2) {
    gemm_core<false>(A, wv, m0, n0, t, As, Bs, acc);
    // normal frag: d = ni*16+lc, s = m0+wr*64+mi*16+lr*4+{0..3}
    int bh = (m0 >> 11) * NHEADS + (n0 >> 6) + wc;
    int scol = (m0 & 2047) + wr * 64;
#pragma unroll
    for (int mi = 0; mi < 4; mi++)
#pragma unroll
      for (int ni = 0; ni < 4; ni++) {
        int d = ni * 16 + lc;
        f32x4 a = acc[mi][ni];
        uint2 pk;
        pk.x = cvtpk(a[0], a[1]);
        pk.y = cvtpk(a[2], a[3]);
        *(uint2*)(VTb + ((size_t)bh * DHEAD + d) * S_LEN + scol + mi * 16 + lr * 4) = pk;
      }
  } else {
    gemm_core<true>(A, z ? wk : wq, m0, n0, t, As, Bs, acc);
    // swapped frag: s = ...+lc, d = ni*16+lr*4+{0..3} = 2 rope pairs
    u16* Oh = z ? Kb : Qb;
    float oscale = z ? 1.0f : 0.125f;  // fold 1/sqrt(DK) into Q
    int h = (n0 >> 6) + wc;
    float fr0[4], fr1[4];
#pragma unroll
    for (int ni = 0; ni < 4; ni++) {
      int i0 = ni * 8 + lr * 2;  // pair index = d/2
      fr0[ni] = exp2f(-0.4152410118407687f * (float)i0);
      fr1[ni] = exp2f(-0.4152410118407687f * (float)(i0 + 1));
    }
#pragma unroll
    for (int mi = 0; mi < 4; mi++) {
      int sg = m0 + wr * 64 + mi * 16 + lc;
      float p = (float)pos[sg];
      int b = sg >> 11, s = sg & 2047;
      u16* dst = Oh + ((size_t)((b * NHEADS + h) * S_LEN + s)) * DHEAD;
#pragma unroll
      for (int ni = 0; ni < 4; ni++) {
        float sn0, cs0, sn1, cs1;
        __sincosf(p * fr0[ni], &sn0, &cs0);
        __sincosf(p * fr1[ni], &sn1, &cs1);
        f32x4 a = acc[mi][ni];
        uint2 pk;
        pk.x = cvtpk((a[0] * cs0 - a[1] * sn0) * oscale,
                     (a[0] * sn0 + a[1] * cs0) * oscale);
        pk.y = cvtpk((a[2] * cs1 - a[3] * sn1) * oscale,
                     (a[2] * sn1 + a[3] * cs1) * oscale);
        *(uint2*)(dst + ni * 16 + lr * 4) = pk;
      }
    }
  }
}

// ---------------- output projection: f32 [M][N], swapped acc -> float4 -----
__global__ __launch_bounds__(256) void gemm_out(const u16* __restrict__ A,
                                                const u16* __restrict__ wo,
                                                float* __restrict__ Of) {
  __shared__ alignas(16) u16 As[2][128 * 64];
  __shared__ alignas(16) u16 Bs[2][128 * 64];
  int m0 = blockIdx.x * 128, n0 = blockIdx.y * 128;
  int t = threadIdx.x;
  int w = t >> 6, lane = t & 63, lr = lane >> 4, lc = lane & 15;
  int wr = w >> 1, wc = w & 1;
  f32x4 acc[4][4] = {};
  gemm_core<true>(A, wo, m0, n0, t, As, Bs, acc);
#pragma unroll
  for (int mi = 0; mi < 4; mi++) {
    int m = m0 + wr * 64 + mi * 16 + lc;
#pragma unroll
    for (int ni = 0; ni < 4; ni++) {
      int n = n0 + wc * 64 + ni * 16 + lr * 4;
      *(f32x4*)(Of + (size_t)m * DMODEL + n) = acc[mi][ni];
    }
  }
}

// ---------------- causal flash attention, v13: split-K gang chunks ----------
struct AttnSt {
  f32x16 oacc[2];
  float mrun, lrun;
};

__device__ __forceinline__ void attn_tile64(
    const char* kbuf, const char* vbuf, int kv0, bool domask,
    const bf16x8 (&qf)[4], int qrow, int h, int ql, AttnSt& st) {
  const float L2E = 1.4426950408889634f;
  int swz = ql & 7;
  // S^T = K * Q^T
  f32x16 sacc[2] = {};
  __builtin_amdgcn_s_setprio(1);
#pragma unroll
  for (int kt = 0; kt < 4; kt++) {
    int c = ((2 * kt + h) ^ swz) << 4;
    bf16x8 k0 = *(const bf16x8*)(kbuf + ql * 128 + c);
    bf16x8 k1 = *(const bf16x8*)(kbuf + (32 + ql) * 128 + c);
    sacc[0] = MFMA32(k0, qf[kt], sacc[0]);
    sacc[1] = MFMA32(k1, qf[kt], sacc[1]);
  }
  __builtin_amdgcn_s_setprio(0);
  if (domask) {
#pragma unroll
    for (int r = 0; r < 16; r++) {
      int kvb = kv0 + (r & 3) + 8 * (r >> 2) + 4 * h;
      if (kvb > qrow) sacc[0][r] = -1e30f;
      if (kvb + 32 > qrow) sacc[1][r] = -1e30f;
    }
  }
  // row max: in-register tree + cross-half shfl
  float t8[8];
#pragma unroll
  for (int r = 0; r < 8; r++)
    t8[r] = fmaxf(fmaxf(sacc[0][r], sacc[0][r + 8]), fmaxf(sacc[1][r], sacc[1][r + 8]));
  float t4a = fmaxf(t8[0], t8[4]), t4b = fmaxf(t8[1], t8[5]);
  float t4c = fmaxf(t8[2], t8[6]), t4d = fmaxf(t8[3], t8[7]);
  float mx = fmaxf(fmaxf(t4a, t4b), fmaxf(t4c, t4d));
  mx = fmaxf(mx, __shfl_xor(mx, 32));
  bool up = mx > st.mrun + 5.5451774444795624f;  // defer-max, THR=8*ln2
  if (__any(up)) {
    float newm = up ? mx : st.mrun;
    float scl = fexp2((st.mrun - newm) * L2E);
    st.mrun = newm;
    st.lrun *= scl;
#pragma unroll
    for (int r = 0; r < 16; r++) { st.oacc[0][r] *= scl; st.oacc[1][r] *= scl; }
  }
  float nm2 = -st.mrun * L2E;
#pragma unroll
  for (int r = 0; r < 16; r++) {
    sacc[0][r] = fexp2(__builtin_fmaf(sacc[0][r], L2E, nm2));
    sacc[1][r] = fexp2(__builtin_fmaf(sacc[1][r], L2E, nm2));
  }
  float u8[8];
#pragma unroll
  for (int r = 0; r < 8; r++)
    u8[r] = (sacc[0][r] + sacc[0][r + 8]) + (sacc[1][r] + sacc[1][r + 8]);
  st.lrun += ((u8[0] + u8[4]) + (u8[1] + u8[5])) + ((u8[2] + u8[6]) + (u8[3] + u8[7]));
  // P^T -> bf16 B-frags
  u32x4 pa[4];
#pragma unroll
  for (int tau = 0; tau < 2; tau++) {
    u32x2 rA = plswap2(cvtpk(sacc[tau][0], sacc[tau][1]), cvtpk(sacc[tau][4], sacc[tau][5]));
    pa[2 * tau][0] = rA[0]; pa[2 * tau][2] = rA[1];
    u32x2 rC = plswap2(cvtpk(sacc[tau][2], sacc[tau][3]), cvtpk(sacc[tau][6], sacc[tau][7]));
    pa[2 * tau][1] = rC[0]; pa[2 * tau][3] = rC[1];
    u32x2 rA1 = plswap2(cvtpk(sacc[tau][8], sacc[tau][9]), cvtpk(sacc[tau][12], sacc[tau][13]));
    pa[2 * tau + 1][0] = rA1[0]; pa[2 * tau + 1][2] = rA1[1];
    u32x2 rC1 = plswap2(cvtpk(sacc[tau][10], sacc[tau][11]), cvtpk(sacc[tau][14], sacc[tau][15]));
    pa[2 * tau + 1][1] = rC1[0]; pa[2 * tau + 1][3] = rC1[1];
  }
  // O^T += V^T * P^T  (V tile [d=64][kv=64], stride 128B)
  __builtin_amdgcn_s_setprio(1);
#pragma unroll
  for (int kt = 0; kt < 4; kt++) {
    int c = ((2 * kt + h) ^ swz) << 4;
    bf16x8 v0 = *(const bf16x8*)(vbuf + ql * 128 + c);
    bf16x8 v1 = *(const bf16x8*)(vbuf + (32 + ql) * 128 + c);
    bf16x8 pb = __builtin_bit_cast(bf16x8, pa[kt]);
    st.oacc[0] = MFMA32(v0, pb, st.oacc[0]);
    st.oacc[1] = MFMA32(v1, pb, st.oacc[1]);
  }
  __builtin_amdgcn_s_setprio(0);
}

__device__ __forceinline__ void attn_store(const AttnSt& st, float lsum,
                                           u16* __restrict__ O, int bh, int qrow, int h) {
  float inv = 1.0f / lsum;
  int b = bh >> 4, hd = bh & 15;
  u16* Orow = O + ((size_t)(b * S_LEN + qrow)) * DMODEL + hd * 64;
#pragma unroll
  for (int dt = 0; dt < 2; dt++)
#pragma unroll
    for (int rr = 0; rr < 4; rr++) {
      uint2 pk;
      pk.x = cvtpk(st.oacc[dt][4 * rr + 0] * inv, st.oacc[dt][4 * rr + 1] * inv);
      pk.y = cvtpk(st.oacc[dt][4 * rr + 2] * inv, st.oacc[dt][4 * rr + 3] * inv);
      *(uint2*)(Orow + 32 * dt + 8 * rr + 4 * h) = pk;
    }
}

__global__ __launch_bounds__(128, 4) void attn_k(const u16* __restrict__ Q,
                                                 const u16* __restrict__ K,
                                                 const u16* __restrict__ VT,
                                                 u16* __restrict__ O,
                                                 char* __restrict__ PB) {
  __shared__ alignas(16) u16 Ks[64 * 64];  // [kv][d], swizzled, 8KB
  __shared__ alignas(16) u16 Vs[64 * 64];  // [d][kv], swizzled, 8KB
  int bh = blockIdx.x;  // fast dim -> bh%8 tracks XCD
  int y = blockIdx.y;   // 0..79: chunk map, heavy q-tiles first
  int qt, c;
  if (y < 32) { qt = 24 + (y & 7); c = y >> 3; }
  else if (y < 56) { int u = y - 32; qt = 16 + (u & 7); c = u >> 3; }
  else if (y < 72) { int u = y - 56; qt = 8 + (u & 7); c = u >> 3; }
  else { qt = y - 72; c = 0; }
  int nt0 = c * 8;
  int nt1 = (nt0 + 7 < qt) ? (nt0 + 7) : qt;  // tiles clipped at diagonal
  bool partial = (qt >= 8);
  int t = threadIdx.x, w = t >> 6, lane = t & 63;
  int ql = lane & 31, h = lane >> 5;
  size_t base = (size_t)bh * (S_LEN * DHEAD);
  int qrow = qt * 64 + w * 32 + ql;
  bf16x8 qf[4];
#pragma unroll
  for (int kt = 0; kt < 4; kt++)
    qf[kt] = *(const bf16x8*)(Q + base + (size_t)qrow * DHEAD + kt * 16 + h * 8);
  AttnSt st;
  st.oacc[0] = f32x16{};
  st.oacc[1] = f32x16{};
  st.mrun = -1e30f;
  st.lrun = 0.0f;
  // staging source (pre-swizzled global chunks; LDS dest linear t*16 + p*2048)
  int srow = t >> 3;                     // 0..15
  int sc = ((t & 7) ^ (srow & 7)) << 3;  // u16 units
  const u16* Kg0 = K + base + (size_t)srow * DHEAD + sc;
  const u16* Vg0 = VT + (size_t)bh * DHEAD * S_LEN + (size_t)srow * S_LEN + sc;
  char* kl = (char*)Ks + w * 1024;
  char* vl = (char*)Vs + w * 1024;
#pragma unroll 1
  for (int s = nt0; s <= nt1; ++s) {
#pragma unroll
    for (int p = 0; p < 4; p++)
      gload16(Kg0 + (size_t)(s * 64 + p * 16) * DHEAD, kl + p * 2048);
#pragma unroll
    for (int p = 0; p < 4; p++)
      gload16(Vg0 + (size_t)(p * 16) * S_LEN + s * 64, vl + p * 2048);
    asm volatile("s_waitcnt vmcnt(0)" ::: "memory");
    __builtin_amdgcn_s_barrier();
    asm volatile("" ::: "memory");
    attn_tile64((const char*)Ks, (const char*)Vs, s * 64, s == qt, qf, qrow, h, ql, st);
    asm volatile("s_waitcnt lgkmcnt(0)" ::: "memory");
    __builtin_amdgcn_s_barrier();
    asm volatile("" ::: "memory");
  }
  float lsum = st.lrun + __shfl_xor(st.lrun, 32);
  if (!partial) {
    attn_store(st, lsum, O, bh, qrow, h);
  } else {
    // slot: qt 8-15: 2 chunks; 16-23: 3; 24-31: 4  (72 slots/bh, 8704B each)
    int off = (qt < 16) ? (qt - 8) * 2 + c
                        : ((qt < 24) ? 16 + (qt - 16) * 3 + c : 40 + (qt - 24) * 4 + c);
    char* pp = PB + (size_t)(bh * 72 + off) * 8704;
    u32x4 wv[4];
#pragma unroll
    for (int dt = 0; dt < 2; dt++)
#pragma unroll
      for (int rr = 0; rr < 4; rr++) {
        int wi = dt * 8 + rr * 2;
        ((u32*)wv)[wi] = cvtpk(st.oacc[dt][4 * rr + 0], st.oacc[dt][4 * rr + 1]);
        ((u32*)wv)[wi + 1] = cvtpk(st.oacc[dt][4 * rr + 2], st.oacc[dt][4 * rr + 3]);
      }
#pragma unroll
    for (int i = 0; i < 4; i++) *(u32x4*)(pp + t * 64 + i * 16) = wv[i];
    if (h == 0) {
      float2 ml;
      ml.x = st.mrun;  // cross-half-combined every tile
      ml.y = lsum;     // combined sum
      *(float2*)(pp + 8192 + (size_t)(w * 32 + ql) * 8) = ml;
    }
  }
}

// ---------------- merge split-K partials (qt >= 8), C in 2..4 ---------------
__global__ __launch_bounds__(128) void merge_k(const char* __restrict__ PB,
                                               u16* __restrict__ O) {
  int bh = blockIdx.x;
  int qt = 8 + blockIdx.y;  // 8..31
  int t = threadIdx.x, w = t >> 6, lane = t & 63;
  int ql = lane & 31, h = lane >> 5;
  int row = w * 32 + ql;
  int C = (qt < 16) ? 2 : ((qt < 24) ? 3 : 4);
  int off = (qt < 16) ? (qt - 8) * 2 : ((qt < 24) ? 16 + (qt - 16) * 3 : 40 + (qt - 24) * 4);
  const char* p = PB + (size_t)(bh * 72 + off) * 8704;
  const float L2E = 1.4426950408889634f;
  float m = -1e30f, l = 0.0f;
  float o[32];
#pragma unroll
  for (int i = 0; i < 32; i++) o[i] = 0.0f;
#pragma unroll 1
  for (int cc = 0; cc < C; ++cc, p += 8704) {
    float2 mlc = *(const float2*)(p + 8192 + (size_t)row * 8);
    float newm = fmaxf(m, mlc.x);
    float s_old = fexp2((m - newm) * L2E);
    float s_new = fexp2((mlc.x - newm) * L2E);
    m = newm;
    l = l * s_old + mlc.y * s_new;
#pragma unroll
    for (int i = 0; i < 16; i++) {
      u32 x = *(const u32*)(p + t * 64 + i * 4);
      o[2 * i] = o[2 * i] * s_old + bf2f((u16)x) * s_new;
      o[2 * i + 1] = o[2 * i + 1] * s_old + bf2f((u16)(x >> 16)) * s_new;
    }
  }
  float inv = 1.0f / l;
  int qrow = qt * 64 + row;
  int b = bh >> 4, hd = bh & 15;
  u16* Orow = O + ((size_t)(b * S_LEN + qrow)) * DMODEL + hd * 64;
#pragma unroll
  for (int dt = 0; dt < 2; dt++)
#pragma unroll
    for (int rr = 0; rr < 4; rr++) {
      int i0 = 2 * (dt * 8 + rr * 2);
      uint2 pk;
      pk.x = cvtpk(o[i0] * inv, o[i0 + 1] * inv);
      pk.y = cvtpk(o[i0 + 2] * inv, o[i0 + 3] * inv);
      *(uint2*)(Orow + 32 * dt + 8 * rr + 4 * h) = pk;
    }
}

// ---------------- launch -----------------------------------------------------
extern "C" void kernel_launch(void* const* d_in, const int* in_sizes, int n_in,
                              void* d_out, int out_size, void* d_ws, size_t ws_size,
                              hipStream_t stream) {
  (void)in_sizes; (void)n_in; (void)out_size; (void)ws_size;
  const float* x = (const float*)d_in[0];
  const int* tpos = (const int*)d_in[1];
  const float* Wq = (const float*)d_in[2];
  const float* Wk = (const float*)d_in[3];
  const float* Wv = (const float*)d_in[4];
  const float* Wo = (const float*)d_in[5];
  char* ws = (char*)d_ws;
  // workspace map (56 MB). PB (20.0 MB attn partials) overlays xb/wq/wk/wv,
  // dead after gemm_qkv. wob lives at +22 until gemm_out.
  u16* xb  = (u16*)(ws + ((size_t)0 << 20));   // 8 MB  (dead after gemm_qkv)
  u16* wqb = (u16*)(ws + ((size_t)8 << 20));   // 2 MB  (dead after gemm_qkv)
  u16* wkb = (u16*)(ws + ((size_t)10 << 20));  // 2 MB  (dead after gemm_qkv)
  u16* wvb = (u16*)(ws + ((size_t)12 << 20));  // 2 MB  (dead after gemm_qkv)
  char* PB = ws;                               // 20.0 MB partials [0,22)
  u16* wob = (u16*)(ws + ((size_t)22 << 20));  // 2 MB
  u16* Qb  = (u16*)(ws + ((size_t)24 << 20));  // 8 MB  [B,H,S,DK] (rope'd, scaled)
  u16* Kb  = (u16*)(ws + ((size_t)32 << 20));  // 8 MB  [B,H,S,DK] (rope'd)
  u16* VTb = (u16*)(ws + ((size_t)40 << 20));  // 8 MB  [B,H,DK,S]
  u16* Ob  = (u16*)(ws + ((size_t)48 << 20));  // 8 MB  [B,S,DMODEL] bf16

  convert_k<<<dim3(1024, 8), 256, 0, stream>>>(x, Wq, Wk, Wv, Wo, xb, wqb, wkb, wvb, wob);
  gemm_qkv<<<dim3(32, 8, 3), 256, 0, stream>>>(xb, wqb, wkb, wvb, Qb, Kb, VTb, tpos);
  attn_k<<<dim3(32, 80), 128, 0, stream>>>(Qb, Kb, VTb, Ob, PB);
  merge_k<<<dim3(32, 24), 128, 0, stream>>>(PB, Ob);
  gemm_out<<<dim3(32, 8), 256, 0, stream>>>(Ob, wob, (float*)d_out);
}